// Round 16
// baseline (149.125 us; speedup 1.0000x reference)
//
#include <hip/hip_runtime.h>
#include <math.h>

#define E_DIM 512
#define H_DIM 8
#define WIN 128
#define L_SEQ 4096
#define B_SZ 2

typedef unsigned short ushort_t;
typedef unsigned int uint_t;
typedef __attribute__((ext_vector_type(8))) __bf16 bf16x8;
typedef __attribute__((ext_vector_type(4))) float f32x4;

// ---------- bf16 helpers (manual, RNE) ----------
__device__ __forceinline__ ushort_t f2bf(float f) {
    uint_t u = __float_as_uint(f);
    u = u + 0x7fffu + ((u >> 16) & 1u);
    return (ushort_t)(u >> 16);
}
__device__ __forceinline__ float bf2f(ushort_t h) {
    return __uint_as_float((uint_t)h << 16);
}

__device__ __forceinline__ void gload16(const ushort_t* g, ushort_t* l) {
    __builtin_amdgcn_global_load_lds(
        (const __attribute__((address_space(1))) void*)g,
        (__attribute__((address_space(3))) void*)l,
        16, 0, 0);
}

// ===== Tile image (16 rows x 32 k = 512 elems = 1 KB) =====
// idx = slot*8 + (k&7), slot = ((k>>3)&3)*16 + (row&15)  [slot = quad*16+ln]
// A-frag & B-frag both read at lane*8 within a tile image.

// ---------- convert: x, w1, w2 -> hi-only tiled bf16 ----------
__global__ __launch_bounds__(256) void convertX(
    const float* __restrict__ x,  ushort_t* __restrict__ xh,
    const float* __restrict__ w1, ushort_t* __restrict__ w1h,
    const float* __restrict__ w2, ushort_t* __restrict__ w2h) {
    int sg = blockIdx.x * 256 + threadIdx.x;
    const float* src; ushort_t* dh;
    if (sg < 524288)      { src = x;  dh = xh; }
    else if (sg < 622592) { src = w1; dh = w1h; sg -= 524288; }
    else                  { src = w2; dh = w2h; sg -= 622592; }
    const int tile = sg >> 6, slot = sg & 63;
    const int row = (tile >> 4) * 16 + (slot & 15);
    const int k   = (tile & 15) * 32 + (slot >> 4) * 8;
    const float4 v0 = *(const float4*)&src[(size_t)row * 512 + k];
    const float4 v1 = *(const float4*)&src[(size_t)row * 512 + k + 4];
    const float vv[8] = {v0.x, v0.y, v0.z, v0.w, v1.x, v1.y, v1.z, v1.w};
    union { ushort_t u[8]; ushort4 v[2]; } h;
    #pragma unroll
    for (int j = 0; j < 8; j++) h.u[j] = f2bf(vv[j]);
    ((ushort4*)(dh + (size_t)sg * 8))[0] = h.v[0];
    ((ushort4*)(dh + (size_t)sg * 8))[1] = h.v[1];
}

// ---------- GEMM1: qkv projection, barrier-free register GEMM ----------
// 128x128 tile, grid (64, 12). Wave = 64x64. No LDS, no __syncthreads:
// A/W fragments loaded directly from tiled global images (L1/L2-hot),
// unroll-2 software pipeline (loads for kt+1 in flight during MFMA of kt).
__global__ __launch_bounds__(256) void gemm_qkv(
    const ushort_t* __restrict__ Ah,
    const ushort_t* __restrict__ Wh,
    const float* __restrict__ bias,
    ushort_t* __restrict__ qTh,
    ushort_t* __restrict__ kTh,
    ushort_t* __restrict__ vTh) {
    const int tid = threadIdx.x, lane = tid & 63, w = tid >> 6;
    const int wm = w & 1, wn = w >> 1, ln = lane & 15, quad = lane >> 4;
    const int bx = blockIdx.x, by = blockIdx.y;
    const int lo8 = lane * 8;

    f32x4 acc[4][4];
    const f32x4 zero = {0.f, 0.f, 0.f, 0.f};
    #pragma unroll
    for (int i = 0; i < 4; i++)
        #pragma unroll
        for (int j = 0; j < 4; j++) acc[i][j] = zero;

    const ushort_t* pa[4];
    const ushort_t* pw[4];
    #pragma unroll
    for (int t = 0; t < 4; t++) {
        pa[t] = Ah + ((size_t)(bx * 8 + wm * 4 + t) * 16) * 512 + lo8;
        pw[t] = Wh + ((size_t)(by * 8 + wn * 4 + t) * 16) * 512 + lo8;
    }

    bf16x8 aA[4], wA[4], aB[4], wB[4];
    #pragma unroll
    for (int t = 0; t < 4; t++) {
        aA[t] = *(const bf16x8*)(pa[t]);
        wA[t] = *(const bf16x8*)(pw[t]);
    }

    for (int kt = 0; kt < 16; kt += 2) {
        // prefetch kt+1 into B set
        #pragma unroll
        for (int t = 0; t < 4; t++) {
            aB[t] = *(const bf16x8*)(pa[t] + (kt + 1) * 512);
            wB[t] = *(const bf16x8*)(pw[t] + (kt + 1) * 512);
        }
        // compute kt on A set
        #pragma unroll
        for (int j = 0; j < 4; j++)
            #pragma unroll
            for (int i = 0; i < 4; i++)
                acc[i][j] = __builtin_amdgcn_mfma_f32_16x16x32_bf16(aA[i], wA[j], acc[i][j], 0, 0, 0);
        // prefetch kt+2 into A set
        if (kt + 2 < 16) {
            #pragma unroll
            for (int t = 0; t < 4; t++) {
                aA[t] = *(const bf16x8*)(pa[t] + (kt + 2) * 512);
                wA[t] = *(const bf16x8*)(pw[t] + (kt + 2) * 512);
            }
        }
        // compute kt+1 on B set
        #pragma unroll
        for (int j = 0; j < 4; j++)
            #pragma unroll
            for (int i = 0; i < 4; i++)
                acc[i][j] = __builtin_amdgcn_mfma_f32_16x16x32_bf16(aB[i], wB[j], acc[i][j], 0, 0, 0);
    }

    // ---- epilogue: C/D layout col=ln (within j-tile), row=quad*4+r ----
    const int b = bx >> 5;
    const int h = 2 * (by & 3) + wn;
    if (by < 8) {
        ushort_t* dh = (by < 4) ? qTh : kTh;
        #pragma unroll
        for (int i = 0; i < 4; i++) {
            const int rt = (bx & 31) * 8 + wm * 4 + i;
            const size_t tb = ((size_t)(b * 8 + h) * 256 + rt) * 2;
            #pragma unroll
            for (int j = 0; j < 4; j++) {
                const float bv = bias[by * 128 + wn * 64 + j * 16 + ln];
                const size_t tile = tb + (j >> 1);
                #pragma unroll
                for (int r = 0; r < 4; r++) {
                    const int slot = ((j * 2 + (ln >> 3)) & 3) * 16 + quad * 4 + r;
                    const size_t idx = tile * 512 + slot * 8 + (ln & 7);
                    dh[idx] = f2bf(acc[i][j][r] + bv);
                }
            }
        }
    } else {
        const int kwin = (bx & 31) * 2 + wm;
        #pragma unroll
        for (int i = 0; i < 4; i++) {
            const int kk = i >> 1;
            #pragma unroll
            for (int j = 0; j < 4; j++) {
                const float bv = bias[by * 128 + wn * 64 + j * 16 + ln];
                const size_t tile = (((size_t)(b * 8 + h) * 64 + kwin) * 4 + j) * 2 + kk;
                #pragma unroll
                for (int r = 0; r < 4; r++) {
                    const int klq = quad * 4 + r;
                    const int slot = ((i & 1) * 2 + (klq >> 3)) * 16 + ln;
                    const size_t idx = tile * 512 + slot * 8 + (klq & 7);
                    vTh[idx] = f2bf(acc[i][j][r] + bv);
                }
            }
        }
    }
}

// ---------- attention: barrier-free, register K/V frags ----------
// 256 thr / 4 waves, 64 q per block, grid (64, 8, 2). No __syncthreads.
// K/V fragments loaded per-wave directly from tiled images; P via own-wave LDS.
__global__ __launch_bounds__(256) void attn_mfma(
    const ushort_t* __restrict__ qTh,
    const ushort_t* __restrict__ kTh,
    const ushort_t* __restrict__ vTh,
    ushort_t* __restrict__ outh) {
    __shared__ __align__(16) ushort_t sP[4 * 1024];

    const int qs = blockIdx.x * 64;
    const int h = blockIdx.y, b = blockIdx.z;
    const int bh = b * 8 + h;
    const int tid = threadIdx.x, lane = tid & 63;
    const int w = tid >> 6, ln = lane & 15, quad = lane >> 4;
    const int lo8 = lane * 8;

    // Q fragments (hi only)
    bf16x8 qf[2];
    {
        const size_t qt = ((size_t)bh * 256 + (qs >> 4) + w) * 2;
        qf[0] = *(const bf16x8*)(qTh + (qt + 0) * 512 + lo8);
        qf[1] = *(const bf16x8*)(qTh + (qt + 1) * 512 + lo8);
    }

    f32x4 oacc[4];
    const f32x4 zero = {0.f, 0.f, 0.f, 0.f};
    #pragma unroll
    for (int dt = 0; dt < 4; dt++) oacc[dt] = zero;
    float m_run[4], l_run[4];
    #pragma unroll
    for (int r = 0; r < 4; r++) { m_run[r] = -1e30f; l_run[r] = 0.f; }

    const float cscale = 0.125f * 1.44269504f;
    const int qlo = qs + 16 * w;

    const ushort_t* kBase = kTh + (size_t)bh * 256 * 2 * 512 + lo8;
    const ushort_t* vBase = vTh + (size_t)bh * 64 * 8 * 512 + lo8;

    for (int kt = 0; kt < 5; kt++) {
        const int ks = qs - 128 + kt * 64;
        // wave-uniform: skip iterations fully outside this wave's window/bounds
        const bool iter_dead = (ks > qlo + 15 + WIN) || (ks + 63 < qlo - WIN) ||
                               (ks >= L_SEQ) || (ks + 63 < 0);
        if (iter_dead) continue;

        // S = Q K^T (1-term), K frags direct from global (live tiles in-bounds)
        f32x4 sacc[4];
        #pragma unroll
        for (int jt = 0; jt < 4; jt++) {
            f32x4 a = zero;
            const int klo = ks + 16 * jt;
            const bool dead = (klo > qlo + 15 + WIN) || (klo + 15 < qlo - WIN) ||
                              (klo >= L_SEQ) || (klo + 15 < 0);
            if (!dead) {
                const int st = ks / 16 + jt;  // exact, in [0,255] for live tiles
                const ushort_t* kb = kBase + (size_t)st * 2 * 512;
                const bf16x8 k0 = *(const bf16x8*)(kb);
                const bf16x8 k1 = *(const bf16x8*)(kb + 512);
                a = __builtin_amdgcn_mfma_f32_16x16x32_bf16(qf[0], k0, a, 0, 0, 0);
                a = __builtin_amdgcn_mfma_f32_16x16x32_bf16(qf[1], k1, a, 0, 0, 0);
            }
            sacc[jt] = a;
        }

        // V frags: issue now so latency hides under softmax VALU
        const int vw = ks >> 6;  // in [0,63] for live iters
        bf16x8 vf[2][4];
        {
            const ushort_t* vb = vBase + (size_t)vw * 8 * 512;
            #pragma unroll
            for (int dt = 0; dt < 4; dt++) {
                vf[0][dt] = *(const bf16x8*)(vb + (dt * 2 + 0) * 512);
                vf[1][dt] = *(const bf16x8*)(vb + (dt * 2 + 1) * 512);
            }
        }

        // mask + online softmax
        float u[4][4];
        #pragma unroll
        for (int jt = 0; jt < 4; jt++) {
            const int kcol = ks + 16 * jt + ln;
            #pragma unroll
            for (int r = 0; r < 4; r++) {
                const int qrow = qlo + quad * 4 + r;
                const int dist = qrow > kcol ? qrow - kcol : kcol - qrow;
                const bool ok = (kcol >= 0) && (kcol < L_SEQ) && (dist >= 1) && (dist <= WIN);
                u[jt][r] = ok ? sacc[jt][r] * cscale : -INFINITY;
            }
        }
        float mk[4];
        #pragma unroll
        for (int r = 0; r < 4; r++)
            mk[r] = fmaxf(fmaxf(u[0][r], u[1][r]), fmaxf(u[2][r], u[3][r]));
        #pragma unroll
        for (int off = 1; off <= 8; off <<= 1)
            #pragma unroll
            for (int r = 0; r < 4; r++)
                mk[r] = fmaxf(mk[r], __shfl_xor(mk[r], off));

        float alpha[4], psum[4], p[4][4];
        #pragma unroll
        for (int r = 0; r < 4; r++) {
            const float mnew = fmaxf(fmaxf(m_run[r], mk[r]), -1e30f);
            alpha[r] = exp2f(m_run[r] - mnew);
            m_run[r] = mnew;
            psum[r] = 0.f;
            #pragma unroll
            for (int jt = 0; jt < 4; jt++) {
                p[jt][r] = exp2f(u[jt][r] - mnew);
                psum[r] += p[jt][r];
            }
        }
        #pragma unroll
        for (int off = 1; off <= 8; off <<= 1)
            #pragma unroll
            for (int r = 0; r < 4; r++)
                psum[r] += __shfl_xor(psum[r], off);
        #pragma unroll
        for (int r = 0; r < 4; r++)
            l_run[r] = l_run[r] * alpha[r] + psum[r];

        #pragma unroll
        for (int dt = 0; dt < 4; dt++)
            #pragma unroll
            for (int r = 0; r < 4; r++)
                oacc[dt][r] *= alpha[r];

        // P (hi only) -> own wave's A-frag tile images (no barrier needed)
        #pragma unroll
        for (int jt = 0; jt < 4; jt++)
            #pragma unroll
            for (int r = 0; r < 4; r++) {
                const int slot = ((jt & 1) * 2 + (ln >> 3)) * 16 + quad * 4 + r;
                sP[w * 1024 + (jt >> 1) * 512 + slot * 8 + (ln & 7)] = f2bf(p[jt][r]);
            }

        // O += P V
        #pragma unroll
        for (int kk = 0; kk < 2; kk++) {
            const bf16x8 pf = *(const bf16x8*)&sP[w * 1024 + kk * 512 + lo8];
            #pragma unroll
            for (int dt = 0; dt < 4; dt++)
                oacc[dt] = __builtin_amdgcn_mfma_f32_16x16x32_bf16(pf, vf[kk][dt], oacc[dt], 0, 0, 0);
        }
    }

    // epilogue: write hi bf16 in GEMM2's A-frag tiled layout
    const int Rt = ((b * L_SEQ + qs) >> 4) + w;
    #pragma unroll
    for (int r = 0; r < 4; r++) {
        const float inv_l = 1.f / l_run[r];
        #pragma unroll
        for (int dt = 0; dt < 4; dt++) {
            const float v = oacc[dt][r] * inv_l;
            const int tile = Rt * 16 + h * 2 + (dt >> 1);
            const int slot = ((dt & 1) * 2 + (ln >> 3)) * 16 + quad * 4 + r;
            const size_t idx = (size_t)tile * 512 + slot * 8 + (ln & 7);
            outh[idx] = f2bf(v);
        }
    }
}

// ---------- GEMM2: out projection, 128x64, 8 waves, BK=64, 1-term, dbuf -----
__global__ __launch_bounds__(512) void gemm_out(
    const ushort_t* __restrict__ Ah,
    const ushort_t* __restrict__ Wh,
    const float* __restrict__ bias, float* __restrict__ C) {
    __shared__ __align__(16) ushort_t sAh[2][16 * 512];
    __shared__ __align__(16) ushort_t sWh[2][8 * 512];

    const int tid = threadIdx.x, lane = tid & 63, w = tid >> 6;
    const int wm = w & 3, wn = w >> 2, ln = lane & 15, quad = lane >> 4;
    const int bx = blockIdx.x, by = blockIdx.y;
    const int lo8 = lane * 8;
    const int wu = __builtin_amdgcn_readfirstlane(w);

    f32x4 acc[2][2];
    const f32x4 zero = {0.f, 0.f, 0.f, 0.f};
    #pragma unroll
    for (int i = 0; i < 2; i++)
        #pragma unroll
        for (int j = 0; j < 2; j++) acc[i][j] = zero;

    const ushort_t* pb[3];
    ushort_t* db0[3];
    ushort_t* db1[3];
    #pragma unroll
    for (int t = 0; t < 3; t++) {
        const int g = wu * 3 + t;
        if (g < 16) {
            pb[t] = Ah + ((size_t)(bx * 8 + (g >> 1)) * 16 + (g & 1)) * 512;
            db0[t] = &sAh[0][g * 512]; db1[t] = &sAh[1][g * 512];
        } else {
            const int u = g - 16;
            pb[t] = Wh + ((size_t)(by * 4 + (u >> 1)) * 16 + (u & 1)) * 512;
            db0[t] = &sWh[0][u * 512]; db1[t] = &sWh[1][u * 512];
        }
    }

    #pragma unroll
    for (int t = 0; t < 3; t++)
        gload16(pb[t] + lo8, db0[t]);

    for (int KT = 0; KT < 8; KT++) {
        __syncthreads();
        if (KT < 7) {
            const int koff = (KT + 1) * 1024;
            if ((KT + 1) & 1) {
                #pragma unroll
                for (int t = 0; t < 3; t++) gload16(pb[t] + koff + lo8, db1[t]);
            } else {
                #pragma unroll
                for (int t = 0; t < 3; t++) gload16(pb[t] + koff + lo8, db0[t]);
            }
        }
        const int cb = KT & 1;
        #pragma unroll
        for (int ks = 0; ks < 2; ks++) {
            bf16x8 fah[2];
            #pragma unroll
            for (int i = 0; i < 2; i++)
                fah[i] = *(const bf16x8*)&sAh[cb][((wm * 2 + i) * 2 + ks) * 512 + lo8];
            #pragma unroll
            for (int j = 0; j < 2; j++) {
                const bf16x8 fbh = *(const bf16x8*)&sWh[cb][((wn * 2 + j) * 2 + ks) * 512 + lo8];
                #pragma unroll
                for (int i = 0; i < 2; i++)
                    acc[i][j] = __builtin_amdgcn_mfma_f32_16x16x32_bf16(fah[i], fbh, acc[i][j], 0, 0, 0);
            }
        }
    }

    #pragma unroll
    for (int i = 0; i < 2; i++) {
        const int row0 = bx * 128 + wm * 32 + i * 16 + quad * 4;
        #pragma unroll
        for (int j = 0; j < 2; j++) {
            const int col = by * 64 + wn * 32 + j * 16 + ln;
            const float bv = bias[col];
            #pragma unroll
            for (int r = 0; r < 4; r++)
                C[(size_t)(row0 + r) * E_DIM + col] = acc[i][j][r] + bv;
        }
    }
}

extern "C" void kernel_launch(void* const* d_in, const int* in_sizes, int n_in,
                              void* d_out, int out_size, void* d_ws, size_t ws_size,
                              hipStream_t stream) {
    const float* x         = (const float*)d_in[0];
    const float* in_proj_w = (const float*)d_in[1];
    const float* in_proj_b = (const float*)d_in[2];
    const float* out_w     = (const float*)d_in[3];
    const float* out_b     = (const float*)d_in[4];
    float* out = (float*)d_out;

    const int N = B_SZ * L_SEQ;  // 8192
    const size_t NE = (size_t)N * E_DIM;  // 4.19M elems

    char* p = (char*)d_ws;
    ushort_t* xh  = (ushort_t*)p; p += NE * 2;
    ushort_t* w1h = (ushort_t*)p; p += (size_t)3 * E_DIM * E_DIM * 2;
    ushort_t* w2h = (ushort_t*)p; p += (size_t)E_DIM * E_DIM * 2;
    ushort_t* qTh = (ushort_t*)p; p += NE * 2;
    ushort_t* kTh = (ushort_t*)p; p += NE * 2;
    ushort_t* vTh = (ushort_t*)p; p += NE * 2;
    ushort_t* ath = (ushort_t*)p; p += NE * 2;
    // total ~46 MB

    convertX<<<2560, 256, 0, stream>>>(x, xh, in_proj_w, w1h, out_w, w2h);

    gemm_qkv<<<dim3(64, 12), 256, 0, stream>>>(
        xh, w1h, in_proj_b, qTh, kTh, vTh);

    attn_mfma<<<dim3(L_SEQ / 64, H_DIM, B_SZ), 256, 0, stream>>>(
        qTh, kTh, vTh, ath);

    gemm_out<<<dim3(64, 8), 512, 0, stream>>>(
        ath, w2h, out_b, out);
}

// Round 17
// 137.096 us; speedup vs baseline: 1.0877x; 1.0877x over previous
//
#include <hip/hip_runtime.h>
#include <math.h>

#define E_DIM 512
#define H_DIM 8
#define WIN 128
#define L_SEQ 4096
#define B_SZ 2

typedef unsigned short ushort_t;
typedef unsigned int uint_t;
typedef __attribute__((ext_vector_type(8))) __bf16 bf16x8;
typedef __attribute__((ext_vector_type(4))) float f32x4;

// ---------- bf16 helpers (manual, RNE) ----------
__device__ __forceinline__ ushort_t f2bf(float f) {
    uint_t u = __float_as_uint(f);
    u = u + 0x7fffu + ((u >> 16) & 1u);
    return (ushort_t)(u >> 16);
}
__device__ __forceinline__ float bf2f(ushort_t h) {
    return __uint_as_float((uint_t)h << 16);
}

__device__ __forceinline__ void gload16(const ushort_t* g, ushort_t* l) {
    __builtin_amdgcn_global_load_lds(
        (const __attribute__((address_space(1))) void*)g,
        (__attribute__((address_space(3))) void*)l,
        16, 0, 0);
}

// ===== Tile image (16 rows x 32 k = 512 elems = 1 KB) =====
// idx = slot*8 + (k&7), slot = ((k>>3)&3)*16 + (row&15)  [slot = quad*16+ln]
// A-frag & B-frag both read at lane*8 within a tile image.

// ---------- convert: x, w1, w2 -> hi-only tiled bf16 (coalesced reads) ------
// Thread gid -> row = gid>>6, kgroup = gid&63: reads 32B contiguous, adjacent
// lanes adjacent -> fully coalesced. Writes 16B/thread at 256B stride; all
// chunks of each 64B line written by in-flight threads -> L2 merges.
__global__ __launch_bounds__(256) void convertX(
    const float* __restrict__ x,  ushort_t* __restrict__ xh,
    const float* __restrict__ w1, ushort_t* __restrict__ w1h,
    const float* __restrict__ w2, ushort_t* __restrict__ w2h) {
    const int gid = blockIdx.x * 256 + threadIdx.x;
    int row = gid >> 6;
    const int kg = gid & 63;
    const float* src; ushort_t* dh;
    if (row < 8192)      { src = x;  dh = xh; }
    else if (row < 9728) { src = w1; dh = w1h; row -= 8192; }
    else                 { src = w2; dh = w2h; row -= 9728; }
    const float4 v0 = *(const float4*)&src[(size_t)row * 512 + kg * 8];
    const float4 v1 = *(const float4*)&src[(size_t)row * 512 + kg * 8 + 4];
    const float vv[8] = {v0.x, v0.y, v0.z, v0.w, v1.x, v1.y, v1.z, v1.w};
    union { ushort_t u[8]; ushort4 v[2]; } h;
    #pragma unroll
    for (int j = 0; j < 8; j++) h.u[j] = f2bf(vv[j]);
    const int tile = (row >> 4) * 16 + (kg >> 2);
    const int slot = (kg & 3) * 16 + (row & 15);
    const size_t idx = (size_t)tile * 512 + slot * 8;
    ((ushort4*)(dh + idx))[0] = h.v[0];
    ((ushort4*)(dh + idx))[1] = h.v[1];
}

// ---------- GEMM1: qkv projection, 1-term (hi x hi), BK=32, 2-deep dbuf ----
// 128x128 tile, grid (64, 12). by<4: q, [4,8): k, >=8: v. All outputs hi-only.
__global__ __launch_bounds__(256) void gemm_qkv(
    const ushort_t* __restrict__ Ah,
    const ushort_t* __restrict__ Wh,
    const float* __restrict__ bias,
    ushort_t* __restrict__ qTh,
    ushort_t* __restrict__ kTh,
    ushort_t* __restrict__ vTh) {
    __shared__ __align__(16) ushort_t sAh[2][8 * 512];
    __shared__ __align__(16) ushort_t sWh[2][8 * 512];

    const int tid = threadIdx.x, lane = tid & 63, w = tid >> 6;
    const int wm = w & 1, wn = w >> 1, ln = lane & 15, quad = lane >> 4;
    const int bx = blockIdx.x, by = blockIdx.y;
    const int lo8 = lane * 8;
    const int wu = __builtin_amdgcn_readfirstlane(w);

    f32x4 acc[4][4];
    const f32x4 zero = {0.f, 0.f, 0.f, 0.f};
    #pragma unroll
    for (int i = 0; i < 4; i++)
        #pragma unroll
        for (int j = 0; j < 4; j++) acc[i][j] = zero;

    // staging: 16 images per k-group (A 8, Wh 8), 4 per wave
    const ushort_t* pb[4];
    ushort_t* db0[4];
    ushort_t* db1[4];
    #pragma unroll
    for (int t = 0; t < 4; t++) {
        const int g = wu * 4 + t;
        if (g < 8) {
            pb[t] = Ah + ((size_t)(bx * 8 + g) * 16) * 512;
            db0[t] = &sAh[0][g * 512]; db1[t] = &sAh[1][g * 512];
        } else {
            const int u = g - 8;
            pb[t] = Wh + ((size_t)(by * 8 + u) * 16) * 512;
            db0[t] = &sWh[0][u * 512]; db1[t] = &sWh[1][u * 512];
        }
    }

    // prologue: stage k-group 0 into buf 0
    #pragma unroll
    for (int t = 0; t < 4; t++)
        gload16(pb[t] + lo8, db0[t]);

    for (int kt = 0; kt < 16; kt++) {
        __syncthreads();
        if (kt < 15) {
            const int koff = (kt + 1) * 512;
            if ((kt + 1) & 1) {
                #pragma unroll
                for (int t = 0; t < 4; t++) gload16(pb[t] + koff + lo8, db1[t]);
            } else {
                #pragma unroll
                for (int t = 0; t < 4; t++) gload16(pb[t] + koff + lo8, db0[t]);
            }
        }
        const int cb = kt & 1;
        bf16x8 fah[4];
        #pragma unroll
        for (int i = 0; i < 4; i++)
            fah[i] = *(const bf16x8*)&sAh[cb][(wm * 4 + i) * 512 + lo8];
        #pragma unroll
        for (int j = 0; j < 4; j++) {
            const bf16x8 fbh = *(const bf16x8*)&sWh[cb][(wn * 4 + j) * 512 + lo8];
            #pragma unroll
            for (int i = 0; i < 4; i++)
                acc[i][j] = __builtin_amdgcn_mfma_f32_16x16x32_bf16(fah[i], fbh, acc[i][j], 0, 0, 0);
        }
    }

    // ---- epilogue: C/D layout col=ln (within j-tile), row=quad*4+r ----
    const int b = bx >> 5;
    const int h = 2 * (by & 3) + wn;
    if (by < 8) {
        ushort_t* dh = (by < 4) ? qTh : kTh;
        #pragma unroll
        for (int i = 0; i < 4; i++) {
            const int rt = (bx & 31) * 8 + wm * 4 + i;
            const size_t tb = ((size_t)(b * 8 + h) * 256 + rt) * 2;
            #pragma unroll
            for (int j = 0; j < 4; j++) {
                const float bv = bias[by * 128 + wn * 64 + j * 16 + ln];
                const size_t tile = tb + (j >> 1);
                #pragma unroll
                for (int r = 0; r < 4; r++) {
                    const int slot = ((j * 2 + (ln >> 3)) & 3) * 16 + quad * 4 + r;
                    const size_t idx = tile * 512 + slot * 8 + (ln & 7);
                    dh[idx] = f2bf(acc[i][j][r] + bv);
                }
            }
        }
    } else {
        const int kwin = (bx & 31) * 2 + wm;
        #pragma unroll
        for (int i = 0; i < 4; i++) {
            const int kk = i >> 1;
            #pragma unroll
            for (int j = 0; j < 4; j++) {
                const float bv = bias[by * 128 + wn * 64 + j * 16 + ln];
                const size_t tile = (((size_t)(b * 8 + h) * 64 + kwin) * 4 + j) * 2 + kk;
                #pragma unroll
                for (int r = 0; r < 4; r++) {
                    const int klq = quad * 4 + r;
                    const int slot = ((i & 1) * 2 + (klq >> 3)) * 16 + ln;
                    const size_t idx = tile * 512 + slot * 8 + (klq & 7);
                    vTh[idx] = f2bf(acc[i][j][r] + bv);
                }
            }
        }
    }
}

// ---------- attention: 128-q blocks, 8 waves, 1-term QK, K/V dbuf ----------
__global__ __launch_bounds__(512) void attn_mfma(
    const ushort_t* __restrict__ qTh,
    const ushort_t* __restrict__ kTh,
    const ushort_t* __restrict__ vTh,
    ushort_t* __restrict__ outh) {
    __shared__ __align__(16) ushort_t sKh[2][8 * 512];
    __shared__ __align__(16) ushort_t sV [2][8 * 512];
    __shared__ __align__(16) ushort_t sP [16 * 512];

    const int qs = blockIdx.x * 128;
    const int h = blockIdx.y, b = blockIdx.z;
    const int bh = b * 8 + h;
    const int tid = threadIdx.x, lane = tid & 63;
    const int w = tid >> 6, ln = lane & 15, quad = lane >> 4;
    const int lo8 = lane * 8;

    // Q fragments (hi only)
    bf16x8 qf[2];
    {
        const size_t qt = ((size_t)bh * 256 + (qs >> 4) + w) * 2;
        qf[0] = *(const bf16x8*)(qTh + (qt + 0) * 512 + lo8);
        qf[1] = *(const bf16x8*)(qTh + (qt + 1) * 512 + lo8);
    }

    f32x4 oacc[4];
    const f32x4 zero = {0.f, 0.f, 0.f, 0.f};
    #pragma unroll
    for (int dt = 0; dt < 4; dt++) oacc[dt] = zero;
    float m_run[4], l_run[4];
    #pragma unroll
    for (int r = 0; r < 4; r++) { m_run[r] = -1e30f; l_run[r] = 0.f; }

    const float cscale = 0.125f * 1.44269504f;
    const int qlo = qs + 16 * w;

    // prologue: kt = 0 into buf 0
    {
        if (w < 4) {
            int st = (qs >> 4) - 8 + w;
            st = st < 0 ? 0 : (st > 255 ? 255 : st);
            const size_t kb = ((size_t)bh * 256 + st) * 2 * 512 + lo8;
            gload16(kTh + kb,       &sKh[0][(w * 2 + 0) * 512]);
            gload16(kTh + kb + 512, &sKh[0][(w * 2 + 1) * 512]);
        } else {
            const int u = w - 4;
            int vw = (qs >> 6) - 2;
            vw = vw < 0 ? 0 : (vw > 63 ? 63 : vw);
            const size_t vb = (((size_t)bh * 64 + vw) * 4 + u) * 2 * 512 + lo8;
            gload16(vTh + vb,       &sV[0][(u * 2 + 0) * 512]);
            gload16(vTh + vb + 512, &sV[0][(u * 2 + 1) * 512]);
        }
    }

    for (int kt = 0; kt < 6; kt++) {
        const int ks = qs - 128 + kt * 64;

        __syncthreads();  // drains stage(kt); all waves done reading buf[(kt+1)&1]

        if (kt < 5) {
            const int nb = (kt + 1) & 1;
            if (w < 4) {
                int st = (qs >> 4) - 8 + (kt + 1) * 4 + w;
                st = st < 0 ? 0 : (st > 255 ? 255 : st);
                const size_t kb = ((size_t)bh * 256 + st) * 2 * 512 + lo8;
                gload16(kTh + kb,       &sKh[nb][(w * 2 + 0) * 512]);
                gload16(kTh + kb + 512, &sKh[nb][(w * 2 + 1) * 512]);
            } else {
                const int u = w - 4;
                int vw = (qs >> 6) - 2 + kt + 1;
                vw = vw < 0 ? 0 : (vw > 63 ? 63 : vw);
                const size_t vb = (((size_t)bh * 64 + vw) * 4 + u) * 2 * 512 + lo8;
                gload16(vTh + vb,       &sV[nb][(u * 2 + 0) * 512]);
                gload16(vTh + vb + 512, &sV[nb][(u * 2 + 1) * 512]);
            }
        }
        const int cb = kt & 1;

        // S = Q K^T (1-term hi x hi)
        f32x4 sacc[4];
        #pragma unroll
        for (int jt = 0; jt < 4; jt++) {
            f32x4 a = zero;
            const int klo = ks + 16 * jt;
            const bool dead = (klo > qlo + 15 + WIN) || (klo + 15 < qlo - WIN) ||
                              (klo >= L_SEQ) || (klo + 15 < 0);
            if (!dead) {
                #pragma unroll
                for (int kk = 0; kk < 2; kk++) {
                    const bf16x8 kh = *(const bf16x8*)&sKh[cb][(jt * 2 + kk) * 512 + lo8];
                    a = __builtin_amdgcn_mfma_f32_16x16x32_bf16(qf[kk], kh, a, 0, 0, 0);
                }
            }
            sacc[jt] = a;
        }

        // mask + online softmax
        float u[4][4];
        #pragma unroll
        for (int jt = 0; jt < 4; jt++) {
            const int kcol = ks + 16 * jt + ln;
            #pragma unroll
            for (int r = 0; r < 4; r++) {
                const int qrow = qlo + quad * 4 + r;
                const int dist = qrow > kcol ? qrow - kcol : kcol - qrow;
                const bool ok = (kcol >= 0) && (kcol < L_SEQ) && (dist >= 1) && (dist <= WIN);
                u[jt][r] = ok ? sacc[jt][r] * cscale : -INFINITY;
            }
        }
        float mk[4];
        #pragma unroll
        for (int r = 0; r < 4; r++)
            mk[r] = fmaxf(fmaxf(u[0][r], u[1][r]), fmaxf(u[2][r], u[3][r]));
        #pragma unroll
        for (int off = 1; off <= 8; off <<= 1)
            #pragma unroll
            for (int r = 0; r < 4; r++)
                mk[r] = fmaxf(mk[r], __shfl_xor(mk[r], off));

        float alpha[4], psum[4], p[4][4];
        #pragma unroll
        for (int r = 0; r < 4; r++) {
            const float mnew = fmaxf(fmaxf(m_run[r], mk[r]), -1e30f);
            alpha[r] = exp2f(m_run[r] - mnew);
            m_run[r] = mnew;
            psum[r] = 0.f;
            #pragma unroll
            for (int jt = 0; jt < 4; jt++) {
                p[jt][r] = exp2f(u[jt][r] - mnew);
                psum[r] += p[jt][r];
            }
        }
        #pragma unroll
        for (int off = 1; off <= 8; off <<= 1)
            #pragma unroll
            for (int r = 0; r < 4; r++)
                psum[r] += __shfl_xor(psum[r], off);
        #pragma unroll
        for (int r = 0; r < 4; r++)
            l_run[r] = l_run[r] * alpha[r] + psum[r];

        #pragma unroll
        for (int dt = 0; dt < 4; dt++)
            #pragma unroll
            for (int r = 0; r < 4; r++)
                oacc[dt][r] *= alpha[r];

        // P (hi only) -> own wave's A-frag tile images
        #pragma unroll
        for (int jt = 0; jt < 4; jt++)
            #pragma unroll
            for (int r = 0; r < 4; r++) {
                const int slot = ((jt & 1) * 2 + (ln >> 3)) * 16 + quad * 4 + r;
                sP[w * 1024 + (jt >> 1) * 512 + slot * 8 + (ln & 7)] = f2bf(p[jt][r]);
            }

        // O += P V (hi x hi)
        #pragma unroll
        for (int kk = 0; kk < 2; kk++) {
            const bf16x8 pf = *(const bf16x8*)&sP[w * 1024 + kk * 512 + lo8];
            #pragma unroll
            for (int dt = 0; dt < 4; dt++) {
                const bf16x8 vf = *(const bf16x8*)&sV[cb][(dt * 2 + kk) * 512 + lo8];
                oacc[dt] = __builtin_amdgcn_mfma_f32_16x16x32_bf16(pf, vf, oacc[dt], 0, 0, 0);
            }
        }
    }

    // epilogue: write hi bf16 in GEMM2's A-frag tiled layout
    const int Rt = ((b * L_SEQ + qs) >> 4) + w;
    #pragma unroll
    for (int r = 0; r < 4; r++) {
        const float inv_l = 1.f / l_run[r];
        #pragma unroll
        for (int dt = 0; dt < 4; dt++) {
            const float v = oacc[dt][r] * inv_l;
            const int tile = Rt * 16 + h * 2 + (dt >> 1);
            const int slot = ((dt & 1) * 2 + (ln >> 3)) * 16 + quad * 4 + r;
            const size_t idx = (size_t)tile * 512 + slot * 8 + (ln & 7);
            outh[idx] = f2bf(v);
        }
    }
}

// ---------- GEMM2: out projection, 128x64, 8 waves, BK=64, 1-term, dbuf -----
__global__ __launch_bounds__(512) void gemm_out(
    const ushort_t* __restrict__ Ah,
    const ushort_t* __restrict__ Wh,
    const float* __restrict__ bias, float* __restrict__ C) {
    __shared__ __align__(16) ushort_t sAh[2][16 * 512];
    __shared__ __align__(16) ushort_t sWh[2][8 * 512];

    const int tid = threadIdx.x, lane = tid & 63, w = tid >> 6;
    const int wm = w & 3, wn = w >> 2, ln = lane & 15, quad = lane >> 4;
    const int bx = blockIdx.x, by = blockIdx.y;
    const int lo8 = lane * 8;
    const int wu = __builtin_amdgcn_readfirstlane(w);

    f32x4 acc[2][2];
    const f32x4 zero = {0.f, 0.f, 0.f, 0.f};
    #pragma unroll
    for (int i = 0; i < 2; i++)
        #pragma unroll
        for (int j = 0; j < 2; j++) acc[i][j] = zero;

    const ushort_t* pb[3];
    ushort_t* db0[3];
    ushort_t* db1[3];
    #pragma unroll
    for (int t = 0; t < 3; t++) {
        const int g = wu * 3 + t;
        if (g < 16) {
            pb[t] = Ah + ((size_t)(bx * 8 + (g >> 1)) * 16 + (g & 1)) * 512;
            db0[t] = &sAh[0][g * 512]; db1[t] = &sAh[1][g * 512];
        } else {
            const int u = g - 16;
            pb[t] = Wh + ((size_t)(by * 4 + (u >> 1)) * 16 + (u & 1)) * 512;
            db0[t] = &sWh[0][u * 512]; db1[t] = &sWh[1][u * 512];
        }
    }

    #pragma unroll
    for (int t = 0; t < 3; t++)
        gload16(pb[t] + lo8, db0[t]);

    for (int KT = 0; KT < 8; KT++) {
        __syncthreads();
        if (KT < 7) {
            const int koff = (KT + 1) * 1024;
            if ((KT + 1) & 1) {
                #pragma unroll
                for (int t = 0; t < 3; t++) gload16(pb[t] + koff + lo8, db1[t]);
            } else {
                #pragma unroll
                for (int t = 0; t < 3; t++) gload16(pb[t] + koff + lo8, db0[t]);
            }
        }
        const int cb = KT & 1;
        #pragma unroll
        for (int ks = 0; ks < 2; ks++) {
            bf16x8 fah[2];
            #pragma unroll
            for (int i = 0; i < 2; i++)
                fah[i] = *(const bf16x8*)&sAh[cb][((wm * 2 + i) * 2 + ks) * 512 + lo8];
            #pragma unroll
            for (int j = 0; j < 2; j++) {
                const bf16x8 fbh = *(const bf16x8*)&sWh[cb][((wn * 2 + j) * 2 + ks) * 512 + lo8];
                #pragma unroll
                for (int i = 0; i < 2; i++)
                    acc[i][j] = __builtin_amdgcn_mfma_f32_16x16x32_bf16(fah[i], fbh, acc[i][j], 0, 0, 0);
            }
        }
    }

    #pragma unroll
    for (int i = 0; i < 2; i++) {
        const int row0 = bx * 128 + wm * 32 + i * 16 + quad * 4;
        #pragma unroll
        for (int j = 0; j < 2; j++) {
            const int col = by * 64 + wn * 32 + j * 16 + ln;
            const float bv = bias[col];
            #pragma unroll
            for (int r = 0; r < 4; r++)
                C[(size_t)(row0 + r) * E_DIM + col] = acc[i][j][r] + bv;
        }
    }
}

extern "C" void kernel_launch(void* const* d_in, const int* in_sizes, int n_in,
                              void* d_out, int out_size, void* d_ws, size_t ws_size,
                              hipStream_t stream) {
    const float* x         = (const float*)d_in[0];
    const float* in_proj_w = (const float*)d_in[1];
    const float* in_proj_b = (const float*)d_in[2];
    const float* out_w     = (const float*)d_in[3];
    const float* out_b     = (const float*)d_in[4];
    float* out = (float*)d_out;

    const int N = B_SZ * L_SEQ;  // 8192
    const size_t NE = (size_t)N * E_DIM;  // 4.19M elems

    char* p = (char*)d_ws;
    ushort_t* xh  = (ushort_t*)p; p += NE * 2;
    ushort_t* w1h = (ushort_t*)p; p += (size_t)3 * E_DIM * E_DIM * 2;
    ushort_t* w2h = (ushort_t*)p; p += (size_t)E_DIM * E_DIM * 2;
    ushort_t* qTh = (ushort_t*)p; p += NE * 2;
    ushort_t* kTh = (ushort_t*)p; p += NE * 2;
    ushort_t* vTh = (ushort_t*)p; p += NE * 2;
    ushort_t* ath = (ushort_t*)p; p += NE * 2;
    // total ~46 MB

    convertX<<<2560, 256, 0, stream>>>(x, xh, in_proj_w, w1h, out_w, w2h);

    gemm_qkv<<<dim3(64, 12), 256, 0, stream>>>(
        xh, w1h, in_proj_b, qTh, kTh, vTh);

    attn_mfma<<<dim3(L_SEQ / 128, H_DIM, B_SZ), 512, 0, stream>>>(
        qTh, kTh, vTh, ath);

    gemm_out<<<dim3(64, 8), 512, 0, stream>>>(
        ath, w2h, out_b, out);
}

// Round 18
// 134.607 us; speedup vs baseline: 1.1079x; 1.0185x over previous
//
#include <hip/hip_runtime.h>
#include <math.h>

#define E_DIM 512
#define H_DIM 8
#define WIN 128
#define L_SEQ 4096
#define B_SZ 2

typedef unsigned short ushort_t;
typedef unsigned int uint_t;
typedef __attribute__((ext_vector_type(8))) __bf16 bf16x8;
typedef __attribute__((ext_vector_type(4))) float f32x4;

// ---------- bf16 helpers (manual, RNE) ----------
__device__ __forceinline__ ushort_t f2bf(float f) {
    uint_t u = __float_as_uint(f);
    u = u + 0x7fffu + ((u >> 16) & 1u);
    return (ushort_t)(u >> 16);
}
__device__ __forceinline__ float bf2f(ushort_t h) {
    return __uint_as_float((uint_t)h << 16);
}

__device__ __forceinline__ void gload16(const ushort_t* g, ushort_t* l) {
    __builtin_amdgcn_global_load_lds(
        (const __attribute__((address_space(1))) void*)g,
        (__attribute__((address_space(3))) void*)l,
        16, 0, 0);
}

// ===== Tile image (16 rows x 32 k = 512 elems = 1 KB) =====
// idx = slot*8 + (k&7), slot = ((k>>3)&3)*16 + (row&15)  [slot = quad*16+ln]
// A-frag & B-frag both read at lane*8 within a tile image.

// ---------- convert: x, w1, w2 -> hi-only tiled bf16 ----------
__global__ __launch_bounds__(256) void convertX(
    const float* __restrict__ x,  ushort_t* __restrict__ xh,
    const float* __restrict__ w1, ushort_t* __restrict__ w1h,
    const float* __restrict__ w2, ushort_t* __restrict__ w2h) {
    int sg = blockIdx.x * 256 + threadIdx.x;
    const float* src; ushort_t* dh;
    if (sg < 524288)      { src = x;  dh = xh; }
    else if (sg < 622592) { src = w1; dh = w1h; sg -= 524288; }
    else                  { src = w2; dh = w2h; sg -= 622592; }
    const int tile = sg >> 6, slot = sg & 63;
    const int row = (tile >> 4) * 16 + (slot & 15);
    const int k   = (tile & 15) * 32 + (slot >> 4) * 8;
    const float4 v0 = *(const float4*)&src[(size_t)row * 512 + k];
    const float4 v1 = *(const float4*)&src[(size_t)row * 512 + k + 4];
    const float vv[8] = {v0.x, v0.y, v0.z, v0.w, v1.x, v1.y, v1.z, v1.w};
    union { ushort_t u[8]; ushort4 v[2]; } h;
    #pragma unroll
    for (int j = 0; j < 8; j++) h.u[j] = f2bf(vv[j]);
    ((ushort4*)(dh + (size_t)sg * 8))[0] = h.v[0];
    ((ushort4*)(dh + (size_t)sg * 8))[1] = h.v[1];
}

// ---------- GEMM1: qkv projection, 1-term (hi x hi), BK=32, 2-deep dbuf ----
// 128x128 tile, grid (64, 12). by<4: q, [4,8): k, >=8: v. All outputs hi-only.
__global__ __launch_bounds__(256) void gemm_qkv(
    const ushort_t* __restrict__ Ah,
    const ushort_t* __restrict__ Wh,
    const float* __restrict__ bias,
    ushort_t* __restrict__ qTh,
    ushort_t* __restrict__ kTh,
    ushort_t* __restrict__ vTh) {
    __shared__ __align__(16) ushort_t sAh[2][8 * 512];
    __shared__ __align__(16) ushort_t sWh[2][8 * 512];

    const int tid = threadIdx.x, lane = tid & 63, w = tid >> 6;
    const int wm = w & 1, wn = w >> 1, ln = lane & 15, quad = lane >> 4;
    const int bx = blockIdx.x, by = blockIdx.y;
    const int lo8 = lane * 8;
    const int wu = __builtin_amdgcn_readfirstlane(w);

    f32x4 acc[4][4];
    const f32x4 zero = {0.f, 0.f, 0.f, 0.f};
    #pragma unroll
    for (int i = 0; i < 4; i++)
        #pragma unroll
        for (int j = 0; j < 4; j++) acc[i][j] = zero;

    // staging: 16 images per k-group (A 8, Wh 8), 4 per wave
    const ushort_t* pb[4];
    ushort_t* db0[4];
    ushort_t* db1[4];
    #pragma unroll
    for (int t = 0; t < 4; t++) {
        const int g = wu * 4 + t;
        if (g < 8) {
            pb[t] = Ah + ((size_t)(bx * 8 + g) * 16) * 512;
            db0[t] = &sAh[0][g * 512]; db1[t] = &sAh[1][g * 512];
        } else {
            const int u = g - 8;
            pb[t] = Wh + ((size_t)(by * 8 + u) * 16) * 512;
            db0[t] = &sWh[0][u * 512]; db1[t] = &sWh[1][u * 512];
        }
    }

    // prologue: stage k-group 0 into buf 0
    #pragma unroll
    for (int t = 0; t < 4; t++)
        gload16(pb[t] + lo8, db0[t]);

    for (int kt = 0; kt < 16; kt++) {
        __syncthreads();
        if (kt < 15) {
            const int koff = (kt + 1) * 512;
            if ((kt + 1) & 1) {
                #pragma unroll
                for (int t = 0; t < 4; t++) gload16(pb[t] + koff + lo8, db1[t]);
            } else {
                #pragma unroll
                for (int t = 0; t < 4; t++) gload16(pb[t] + koff + lo8, db0[t]);
            }
        }
        const int cb = kt & 1;
        bf16x8 fah[4];
        #pragma unroll
        for (int i = 0; i < 4; i++)
            fah[i] = *(const bf16x8*)&sAh[cb][(wm * 4 + i) * 512 + lo8];
        #pragma unroll
        for (int j = 0; j < 4; j++) {
            const bf16x8 fbh = *(const bf16x8*)&sWh[cb][(wn * 4 + j) * 512 + lo8];
            #pragma unroll
            for (int i = 0; i < 4; i++)
                acc[i][j] = __builtin_amdgcn_mfma_f32_16x16x32_bf16(fah[i], fbh, acc[i][j], 0, 0, 0);
        }
    }

    // ---- epilogue: C/D layout col=ln (within j-tile), row=quad*4+r ----
    const int b = bx >> 5;
    const int h = 2 * (by & 3) + wn;
    if (by < 8) {
        ushort_t* dh = (by < 4) ? qTh : kTh;
        #pragma unroll
        for (int i = 0; i < 4; i++) {
            const int rt = (bx & 31) * 8 + wm * 4 + i;
            const size_t tb = ((size_t)(b * 8 + h) * 256 + rt) * 2;
            #pragma unroll
            for (int j = 0; j < 4; j++) {
                const float bv = bias[by * 128 + wn * 64 + j * 16 + ln];
                const size_t tile = tb + (j >> 1);
                #pragma unroll
                for (int r = 0; r < 4; r++) {
                    const int slot = ((j * 2 + (ln >> 3)) & 3) * 16 + quad * 4 + r;
                    const size_t idx = tile * 512 + slot * 8 + (ln & 7);
                    dh[idx] = f2bf(acc[i][j][r] + bv);
                }
            }
        }
    } else {
        const int kwin = (bx & 31) * 2 + wm;
        #pragma unroll
        for (int i = 0; i < 4; i++) {
            const int kk = i >> 1;
            #pragma unroll
            for (int j = 0; j < 4; j++) {
                const float bv = bias[by * 128 + wn * 64 + j * 16 + ln];
                const size_t tile = (((size_t)(b * 8 + h) * 64 + kwin) * 4 + j) * 2 + kk;
                #pragma unroll
                for (int r = 0; r < 4; r++) {
                    const int klq = quad * 4 + r;
                    const int slot = ((i & 1) * 2 + (klq >> 3)) * 16 + ln;
                    const size_t idx = tile * 512 + slot * 8 + (klq & 7);
                    vTh[idx] = f2bf(acc[i][j][r] + bv);
                }
            }
        }
    }
}

// ---------- attention: 128-q blocks, 8 waves, 1-term QK, K/V dbuf ----------
__global__ __launch_bounds__(512) void attn_mfma(
    const ushort_t* __restrict__ qTh,
    const ushort_t* __restrict__ kTh,
    const ushort_t* __restrict__ vTh,
    ushort_t* __restrict__ outh) {
    __shared__ __align__(16) ushort_t sKh[2][8 * 512];
    __shared__ __align__(16) ushort_t sV [2][8 * 512];
    __shared__ __align__(16) ushort_t sP [16 * 512];

    const int qs = blockIdx.x * 128;
    const int h = blockIdx.y, b = blockIdx.z;
    const int bh = b * 8 + h;
    const int tid = threadIdx.x, lane = tid & 63;
    const int w = tid >> 6, ln = lane & 15, quad = lane >> 4;
    const int lo8 = lane * 8;

    // Q fragments (hi only)
    bf16x8 qf[2];
    {
        const size_t qt = ((size_t)bh * 256 + (qs >> 4) + w) * 2;
        qf[0] = *(const bf16x8*)(qTh + (qt + 0) * 512 + lo8);
        qf[1] = *(const bf16x8*)(qTh + (qt + 1) * 512 + lo8);
    }

    f32x4 oacc[4];
    const f32x4 zero = {0.f, 0.f, 0.f, 0.f};
    #pragma unroll
    for (int dt = 0; dt < 4; dt++) oacc[dt] = zero;
    float m_run[4], l_run[4];
    #pragma unroll
    for (int r = 0; r < 4; r++) { m_run[r] = -1e30f; l_run[r] = 0.f; }

    const float cscale = 0.125f * 1.44269504f;
    const int qlo = qs + 16 * w;

    // prologue: kt = 0 into buf 0
    {
        if (w < 4) {
            int st = (qs >> 4) - 8 + w;
            st = st < 0 ? 0 : (st > 255 ? 255 : st);
            const size_t kb = ((size_t)bh * 256 + st) * 2 * 512 + lo8;
            gload16(kTh + kb,       &sKh[0][(w * 2 + 0) * 512]);
            gload16(kTh + kb + 512, &sKh[0][(w * 2 + 1) * 512]);
        } else {
            const int u = w - 4;
            int vw = (qs >> 6) - 2;
            vw = vw < 0 ? 0 : (vw > 63 ? 63 : vw);
            const size_t vb = (((size_t)bh * 64 + vw) * 4 + u) * 2 * 512 + lo8;
            gload16(vTh + vb,       &sV[0][(u * 2 + 0) * 512]);
            gload16(vTh + vb + 512, &sV[0][(u * 2 + 1) * 512]);
        }
    }

    for (int kt = 0; kt < 6; kt++) {
        const int ks = qs - 128 + kt * 64;

        __syncthreads();  // drains stage(kt); all waves done reading buf[(kt+1)&1]

        if (kt < 5) {
            const int nb = (kt + 1) & 1;
            if (w < 4) {
                int st = (qs >> 4) - 8 + (kt + 1) * 4 + w;
                st = st < 0 ? 0 : (st > 255 ? 255 : st);
                const size_t kb = ((size_t)bh * 256 + st) * 2 * 512 + lo8;
                gload16(kTh + kb,       &sKh[nb][(w * 2 + 0) * 512]);
                gload16(kTh + kb + 512, &sKh[nb][(w * 2 + 1) * 512]);
            } else {
                const int u = w - 4;
                int vw = (qs >> 6) - 2 + kt + 1;
                vw = vw < 0 ? 0 : (vw > 63 ? 63 : vw);
                const size_t vb = (((size_t)bh * 64 + vw) * 4 + u) * 2 * 512 + lo8;
                gload16(vTh + vb,       &sV[nb][(u * 2 + 0) * 512]);
                gload16(vTh + vb + 512, &sV[nb][(u * 2 + 1) * 512]);
            }
        }
        const int cb = kt & 1;

        // S = Q K^T (1-term hi x hi)
        f32x4 sacc[4];
        #pragma unroll
        for (int jt = 0; jt < 4; jt++) {
            f32x4 a = zero;
            const int klo = ks + 16 * jt;
            const bool dead = (klo > qlo + 15 + WIN) || (klo + 15 < qlo - WIN) ||
                              (klo >= L_SEQ) || (klo + 15 < 0);
            if (!dead) {
                #pragma unroll
                for (int kk = 0; kk < 2; kk++) {
                    const bf16x8 kh = *(const bf16x8*)&sKh[cb][(jt * 2 + kk) * 512 + lo8];
                    a = __builtin_amdgcn_mfma_f32_16x16x32_bf16(qf[kk], kh, a, 0, 0, 0);
                }
            }
            sacc[jt] = a;
        }

        // mask + online softmax
        float u[4][4];
        #pragma unroll
        for (int jt = 0; jt < 4; jt++) {
            const int kcol = ks + 16 * jt + ln;
            #pragma unroll
            for (int r = 0; r < 4; r++) {
                const int qrow = qlo + quad * 4 + r;
                const int dist = qrow > kcol ? qrow - kcol : kcol - qrow;
                const bool ok = (kcol >= 0) && (kcol < L_SEQ) && (dist >= 1) && (dist <= WIN);
                u[jt][r] = ok ? sacc[jt][r] * cscale : -INFINITY;
            }
        }
        float mk[4];
        #pragma unroll
        for (int r = 0; r < 4; r++)
            mk[r] = fmaxf(fmaxf(u[0][r], u[1][r]), fmaxf(u[2][r], u[3][r]));
        #pragma unroll
        for (int off = 1; off <= 8; off <<= 1)
            #pragma unroll
            for (int r = 0; r < 4; r++)
                mk[r] = fmaxf(mk[r], __shfl_xor(mk[r], off));

        float alpha[4], psum[4], p[4][4];
        #pragma unroll
        for (int r = 0; r < 4; r++) {
            const float mnew = fmaxf(fmaxf(m_run[r], mk[r]), -1e30f);
            alpha[r] = exp2f(m_run[r] - mnew);
            m_run[r] = mnew;
            psum[r] = 0.f;
            #pragma unroll
            for (int jt = 0; jt < 4; jt++) {
                p[jt][r] = exp2f(u[jt][r] - mnew);
                psum[r] += p[jt][r];
            }
        }
        #pragma unroll
        for (int off = 1; off <= 8; off <<= 1)
            #pragma unroll
            for (int r = 0; r < 4; r++)
                psum[r] += __shfl_xor(psum[r], off);
        #pragma unroll
        for (int r = 0; r < 4; r++)
            l_run[r] = l_run[r] * alpha[r] + psum[r];

        #pragma unroll
        for (int dt = 0; dt < 4; dt++)
            #pragma unroll
            for (int r = 0; r < 4; r++)
                oacc[dt][r] *= alpha[r];

        // P (hi only) -> own wave's A-frag tile images
        #pragma unroll
        for (int jt = 0; jt < 4; jt++)
            #pragma unroll
            for (int r = 0; r < 4; r++) {
                const int slot = ((jt & 1) * 2 + (ln >> 3)) * 16 + quad * 4 + r;
                sP[w * 1024 + (jt >> 1) * 512 + slot * 8 + (ln & 7)] = f2bf(p[jt][r]);
            }

        // O += P V (hi x hi)
        #pragma unroll
        for (int kk = 0; kk < 2; kk++) {
            const bf16x8 pf = *(const bf16x8*)&sP[w * 1024 + kk * 512 + lo8];
            #pragma unroll
            for (int dt = 0; dt < 4; dt++) {
                const bf16x8 vf = *(const bf16x8*)&sV[cb][(dt * 2 + kk) * 512 + lo8];
                oacc[dt] = __builtin_amdgcn_mfma_f32_16x16x32_bf16(pf, vf, oacc[dt], 0, 0, 0);
            }
        }
    }

    // epilogue: write hi bf16 in GEMM2's A-frag tiled layout
    const int Rt = ((b * L_SEQ + qs) >> 4) + w;
    #pragma unroll
    for (int r = 0; r < 4; r++) {
        const float inv_l = 1.f / l_run[r];
        #pragma unroll
        for (int dt = 0; dt < 4; dt++) {
            const float v = oacc[dt][r] * inv_l;
            const int tile = Rt * 16 + h * 2 + (dt >> 1);
            const int slot = ((dt & 1) * 2 + (ln >> 3)) * 16 + quad * 4 + r;
            const size_t idx = (size_t)tile * 512 + slot * 8 + (ln & 7);
            outh[idx] = f2bf(v);
        }
    }
}

// ---------- GEMM2: out projection, 128x64, 8 waves, BK=64, 1-term, dbuf -----
__global__ __launch_bounds__(512) void gemm_out(
    const ushort_t* __restrict__ Ah,
    const ushort_t* __restrict__ Wh,
    const float* __restrict__ bias, float* __restrict__ C) {
    __shared__ __align__(16) ushort_t sAh[2][16 * 512];
    __shared__ __align__(16) ushort_t sWh[2][8 * 512];

    const int tid = threadIdx.x, lane = tid & 63, w = tid >> 6;
    const int wm = w & 3, wn = w >> 2, ln = lane & 15, quad = lane >> 4;
    const int bx = blockIdx.x, by = blockIdx.y;
    const int lo8 = lane * 8;
    const int wu = __builtin_amdgcn_readfirstlane(w);

    f32x4 acc[2][2];
    const f32x4 zero = {0.f, 0.f, 0.f, 0.f};
    #pragma unroll
    for (int i = 0; i < 2; i++)
        #pragma unroll
        for (int j = 0; j < 2; j++) acc[i][j] = zero;

    const ushort_t* pb[3];
    ushort_t* db0[3];
    ushort_t* db1[3];
    #pragma unroll
    for (int t = 0; t < 3; t++) {
        const int g = wu * 3 + t;
        if (g < 16) {
            pb[t] = Ah + ((size_t)(bx * 8 + (g >> 1)) * 16 + (g & 1)) * 512;
            db0[t] = &sAh[0][g * 512]; db1[t] = &sAh[1][g * 512];
        } else {
            const int u = g - 16;
            pb[t] = Wh + ((size_t)(by * 4 + (u >> 1)) * 16 + (u & 1)) * 512;
            db0[t] = &sWh[0][u * 512]; db1[t] = &sWh[1][u * 512];
        }
    }

    #pragma unroll
    for (int t = 0; t < 3; t++)
        gload16(pb[t] + lo8, db0[t]);

    for (int KT = 0; KT < 8; KT++) {
        __syncthreads();
        if (KT < 7) {
            const int koff = (KT + 1) * 1024;
            if ((KT + 1) & 1) {
                #pragma unroll
                for (int t = 0; t < 3; t++) gload16(pb[t] + koff + lo8, db1[t]);
            } else {
                #pragma unroll
                for (int t = 0; t < 3; t++) gload16(pb[t] + koff + lo8, db0[t]);
            }
        }
        const int cb = KT & 1;
        #pragma unroll
        for (int ks = 0; ks < 2; ks++) {
            bf16x8 fah[2];
            #pragma unroll
            for (int i = 0; i < 2; i++)
                fah[i] = *(const bf16x8*)&sAh[cb][((wm * 2 + i) * 2 + ks) * 512 + lo8];
            #pragma unroll
            for (int j = 0; j < 2; j++) {
                const bf16x8 fbh = *(const bf16x8*)&sWh[cb][((wn * 2 + j) * 2 + ks) * 512 + lo8];
                #pragma unroll
                for (int i = 0; i < 2; i++)
                    acc[i][j] = __builtin_amdgcn_mfma_f32_16x16x32_bf16(fah[i], fbh, acc[i][j], 0, 0, 0);
            }
        }
    }

    #pragma unroll
    for (int i = 0; i < 2; i++) {
        const int row0 = bx * 128 + wm * 32 + i * 16 + quad * 4;
        #pragma unroll
        for (int j = 0; j < 2; j++) {
            const int col = by * 64 + wn * 32 + j * 16 + ln;
            const float bv = bias[col];
            #pragma unroll
            for (int r = 0; r < 4; r++)
                C[(size_t)(row0 + r) * E_DIM + col] = acc[i][j][r] + bv;
        }
    }
}

extern "C" void kernel_launch(void* const* d_in, const int* in_sizes, int n_in,
                              void* d_out, int out_size, void* d_ws, size_t ws_size,
                              hipStream_t stream) {
    const float* x         = (const float*)d_in[0];
    const float* in_proj_w = (const float*)d_in[1];
    const float* in_proj_b = (const float*)d_in[2];
    const float* out_w     = (const float*)d_in[3];
    const float* out_b     = (const float*)d_in[4];
    float* out = (float*)d_out;

    const int N = B_SZ * L_SEQ;  // 8192
    const size_t NE = (size_t)N * E_DIM;  // 4.19M elems

    char* p = (char*)d_ws;
    ushort_t* xh  = (ushort_t*)p; p += NE * 2;
    ushort_t* w1h = (ushort_t*)p; p += (size_t)3 * E_DIM * E_DIM * 2;
    ushort_t* w2h = (ushort_t*)p; p += (size_t)E_DIM * E_DIM * 2;
    ushort_t* qTh = (ushort_t*)p; p += NE * 2;
    ushort_t* kTh = (ushort_t*)p; p += NE * 2;
    ushort_t* vTh = (ushort_t*)p; p += NE * 2;
    ushort_t* ath = (ushort_t*)p; p += NE * 2;
    // total ~46 MB

    convertX<<<2560, 256, 0, stream>>>(x, xh, in_proj_w, w1h, out_w, w2h);

    gemm_qkv<<<dim3(64, 12), 256, 0, stream>>>(
        xh, w1h, in_proj_b, qTh, kTh, vTh);

    attn_mfma<<<dim3(L_SEQ / 128, H_DIM, B_SZ), 512, 0, stream>>>(
        qTh, kTh, vTh, ath);

    gemm_out<<<dim3(64, 8), 512, 0, stream>>>(
        ath, w2h, out_b, out);
}